// Round 4
// baseline (210.230 us; speedup 1.0000x reference)
//
#include <hip/hip_runtime.h>
#include <hip/hip_bf16.h>
#include <math.h>

// Problem constants
#define Bb 4
#define Ss 2048
#define Hh 1024
#define Ff 513           // H/2 + 1 rfft bins
#define FEAT 1026        // cos||sin feature length
#define KP2 1056         // padded feature K (33 * 32)

typedef __attribute__((ext_vector_type(8))) short bf16x8;
typedef __attribute__((ext_vector_type(4))) float f32x4;

typedef const __attribute__((address_space(1))) void GVoid;
typedef __attribute__((address_space(3))) void LVoid;

// padded LDS index for float2 arrays: breaks power-of-2 stride conflicts
#define PADI(i) ((i) + ((i) >> 4))

__device__ __forceinline__ float2 cmul(float2 a, float2 b) {
  return make_float2(a.x * b.x - a.y * b.y, a.x * b.y + a.y * b.x);
}

__device__ __forceinline__ unsigned short bf16bits(float x) {
  __hip_bfloat16 h = __float2bfloat16(x);
  return *reinterpret_cast<unsigned short*>(&h);
}

// ---------------------------------------------------------------------------
// Kernel 1: packed-real FFT. One block per (b,s) row-pair: z = Q_row + i*K_row,
// single 1024-pt radix-4 DIT FFT (5 stages), untangle, unit-normalize,
// emit bf16 [cos||sin] features.
// ---------------------------------------------------------------------------
__global__ __launch_bounds__(256) void fft_phase_kernel(
    const float* __restrict__ Q, const float* __restrict__ Kin,
    __hip_bfloat16* __restrict__ FQ, __hip_bfloat16* __restrict__ FK) {
  const int row = blockIdx.x;                     // 0 .. B*S-1
  const float* qs = Q   + (size_t)row * Hh;
  const float* ks = Kin + (size_t)row * Hh;
  __hip_bfloat16* fq = FQ + (size_t)row * KP2;
  __hip_bfloat16* fk = FK + (size_t)row * KP2;

  __shared__ float2 data[PADI(1023) + 1];
  __shared__ float2 tw[1024];
  const int tid = threadIdx.x;

#pragma unroll
  for (int e = 0; e < 4; ++e) {
    const int m = tid + e * 256;
    float s, c;
    sincosf(-6.283185307179586f * (float)m * (1.0f / 1024.0f), &s, &c);
    tw[m] = make_float2(c, s);
  }
#pragma unroll
  for (int e = 0; e < 4; ++e) {
    const int n = tid + e * 256;
    const int r4 = ((n & 3) << 8) | (((n >> 2) & 3) << 6) | (((n >> 4) & 3) << 4)
                 | (((n >> 6) & 3) << 2) | ((n >> 8) & 3);
    data[PADI(r4)] = make_float2(qs[n], ks[n]);
  }
  __syncthreads();

  int quarter = 1, step = 256;
  for (int s = 0; s < 5; ++s) {
    const int j = tid & (quarter - 1);
    const int pos = 4 * tid - 3 * j;
    const float2 x0 = data[PADI(pos)];
    const float2 x1 = data[PADI(pos + quarter)];
    const float2 x2 = data[PADI(pos + 2 * quarter)];
    const float2 x3 = data[PADI(pos + 3 * quarter)];
    const int e1 = j * step;
    const float2 a1 = cmul(x1, tw[e1]);
    const float2 a2 = cmul(x2, tw[2 * e1]);
    const float2 a3 = cmul(x3, tw[3 * e1]);
    const float2 t0 = make_float2(x0.x + a2.x, x0.y + a2.y);
    const float2 t1 = make_float2(x0.x - a2.x, x0.y - a2.y);
    const float2 t2 = make_float2(a1.x + a3.x, a1.y + a3.y);
    const float2 t3 = make_float2(a1.x - a3.x, a1.y - a3.y);
    data[PADI(pos)]               = make_float2(t0.x + t2.x, t0.y + t2.y);
    data[PADI(pos + quarter)]     = make_float2(t1.x + t3.y, t1.y - t3.x);
    data[PADI(pos + 2 * quarter)] = make_float2(t0.x - t2.x, t0.y - t2.y);
    data[PADI(pos + 3 * quarter)] = make_float2(t1.x - t3.y, t1.y + t3.x);
    __syncthreads();
    quarter <<= 2; step >>= 2;
  }

  for (int f = tid; f <= 512; f += 256) {
    const float2 z1 = data[PADI(f)];
    const float2 z2 = data[PADI((1024 - f) & 1023)];
    const float qr = z1.x + z2.x, qi = z1.y - z2.y;
    const float kr = z1.y + z2.y, ki = z2.x - z1.x;
    float qc, qsn, kc, ksn;
    const float qm2 = qr * qr + qi * qi;
    if (qm2 > 1e-30f) { const float iv = rsqrtf(qm2); qc = qr * iv; qsn = qi * iv; }
    else              { qc = 1.0f; qsn = 0.0f; }
    const float km2 = kr * kr + ki * ki;
    if (km2 > 1e-30f) { const float iv = rsqrtf(km2); kc = kr * iv; ksn = ki * iv; }
    else              { kc = 1.0f; ksn = 0.0f; }
    fq[f] = __float2bfloat16(qc); fq[Ff + f] = __float2bfloat16(qsn);
    fk[f] = __float2bfloat16(kc); fk[Ff + f] = __float2bfloat16(ksn);
  }
  for (int p = FEAT + tid; p < KP2; p += 256) {
    fq[p] = __float2bfloat16(0.0f);
    fk[p] = __float2bfloat16(0.0f);
  }
}

// ---------------------------------------------------------------------------
// Kernel 2: V [B,S,H] fp32 -> Vt [B,H,S] bf16 (transpose, LDS 32x33 tile)
// ---------------------------------------------------------------------------
__global__ __launch_bounds__(256) void vt_kernel(
    const float* __restrict__ V, __hip_bfloat16* __restrict__ Vt) {
  const int b = blockIdx.z;
  const int h0 = blockIdx.x * 32;
  const int s0 = blockIdx.y * 32;
  __shared__ float t[32][33];
  const int tid = threadIdx.x;
  const int c = tid & 31;
  const int r8 = tid >> 5;
  const float* Vb = V + (size_t)b * Ss * Hh;
#pragma unroll
  for (int e = 0; e < 4; ++e) {
    const int r = r8 + e * 8;
    t[r][c] = Vb[(size_t)(s0 + r) * Hh + h0 + c];
  }
  __syncthreads();
  __hip_bfloat16* O = Vt + (size_t)b * Hh * Ss;
#pragma unroll
  for (int e = 0; e < 4; ++e) {
    const int hh = r8 + e * 8;
    O[(size_t)(h0 + hh) * Ss + s0 + c] = __float2bfloat16(t[c][hh]);
  }
}

// ---------------------------------------------------------------------------
// bf16 MFMA GEMM, C = A * B^T, 128x128 tile, BK=32, 4 waves.
// 2-phase double-buffered (T3-min): STAGE(next) issued BEFORE ds_read+MFMA
// on current buffer; ONE __syncthreads per K-step (its built-in
// vmcnt(0)+lgkmcnt(0) drain provides all ordering).
// EPI 0: C = acc/513 (scores; +1 dropped, softmax shift-invariant).
// EPI 1: C = acc (PV output).
// ---------------------------------------------------------------------------
template<int K, int LDA, int LDB, int LDC, int EPI>
__global__ __launch_bounds__(256) void gemm_bt(
    const __hip_bfloat16* __restrict__ Ag, const __hip_bfloat16* __restrict__ Bg,
    float* __restrict__ Cg, size_t strA, size_t strB, size_t strC) {
  const int b = blockIdx.z;
  const int i0 = blockIdx.y * 128;
  const int j0 = blockIdx.x * 128;
  const char* Ab = (const char*)(Ag + (size_t)b * strA);
  const char* Bp = (const char*)(Bg + (size_t)b * strB);
  float* C = Cg + (size_t)b * strC;

  __shared__ short As[2][4096];   // 8 subtiles x (4 kchunk x 16 row x 8 bf16)
  __shared__ short Bs[2][4096];

  const int tid = threadIdx.x;
  const int lane = tid & 63;
  const int w = tid >> 6;
  const int wm = w >> 1, wn = w & 1;
  const int lrow = lane & 15;
  const int lchunk = lane >> 4;

  f32x4 acc[4][4];
#pragma unroll
  for (int m = 0; m < 4; ++m)
#pragma unroll
    for (int n = 0; n < 4; ++n)
      acc[m][n] = (f32x4){0.0f, 0.0f, 0.0f, 0.0f};

  const size_t aoff0 = (size_t)(i0 + (w    ) * 16 + lrow) * (LDA * 2) + lchunk * 16;
  const size_t aoff1 = (size_t)(i0 + (w + 4) * 16 + lrow) * (LDA * 2) + lchunk * 16;
  const size_t boff0 = (size_t)(j0 + (w    ) * 16 + lrow) * (LDB * 2) + lchunk * 16;
  const size_t boff1 = (size_t)(j0 + (w + 4) * 16 + lrow) * (LDB * 2) + lchunk * 16;

#define STAGE(buf, k0)                                                                              \
  do {                                                                                              \
    const size_t kb = (size_t)(k0) * 2;                                                             \
    __builtin_amdgcn_global_load_lds((GVoid*)(Ab + aoff0 + kb), (LVoid*)&As[buf][(w    ) * 512], 16, 0, 0); \
    __builtin_amdgcn_global_load_lds((GVoid*)(Ab + aoff1 + kb), (LVoid*)&As[buf][(w + 4) * 512], 16, 0, 0); \
    __builtin_amdgcn_global_load_lds((GVoid*)(Bp + boff0 + kb), (LVoid*)&Bs[buf][(w    ) * 512], 16, 0, 0); \
    __builtin_amdgcn_global_load_lds((GVoid*)(Bp + boff1 + kb), (LVoid*)&Bs[buf][(w + 4) * 512], 16, 0, 0); \
  } while (0)

  STAGE(0, 0);
  __syncthreads();                 // drain prologue loads
  int cur = 0;

  for (int k0 = 0; k0 < K; k0 += 32) {
    if (k0 + 32 < K) STAGE(cur ^ 1, k0 + 32);   // prefetch next tile, in flight during compute

    bf16x8 af[4], bfr[4];
#pragma unroll
    for (int m = 0; m < 4; ++m)
      af[m] = *(const bf16x8*)&As[cur][(wm * 4 + m) * 512 + lchunk * 128 + lrow * 8];
#pragma unroll
    for (int n = 0; n < 4; ++n)
      bfr[n] = *(const bf16x8*)&Bs[cur][(wn * 4 + n) * 512 + lchunk * 128 + lrow * 8];
#pragma unroll
    for (int m = 0; m < 4; ++m)
#pragma unroll
      for (int n = 0; n < 4; ++n)
        acc[m][n] = __builtin_amdgcn_mfma_f32_16x16x32_bf16(af[m], bfr[n], acc[m][n], 0, 0, 0);

    __syncthreads();               // vmcnt(0)+lgkmcnt(0)+barrier: next tile ready, reads done
    cur ^= 1;
  }
#undef STAGE

  const int r4 = (lane >> 4) * 4;
  const int cc = lane & 15;
#pragma unroll
  for (int m = 0; m < 4; ++m) {
    const int ib = i0 + wm * 64 + m * 16 + r4;
#pragma unroll
    for (int n = 0; n < 4; ++n) {
      const int j = j0 + wn * 64 + n * 16 + cc;
#pragma unroll
      for (int r = 0; r < 4; ++r) {
        float v = acc[m][n][r];
        if (EPI == 0) v = v * (1.0f / 513.0f);
        C[(size_t)(ib + r) * LDC + j] = v;
      }
    }
  }
}

// ---------------------------------------------------------------------------
// Kernel 3: in-place row softmax over 2048 cols + bf16 copy for PV GEMM.
// Vectorized: 8 contiguous elems/thread (float4 x2 in, float4 x2 + bf16x8 out).
// ---------------------------------------------------------------------------
__global__ __launch_bounds__(256) void softmax_kernel(
    float* __restrict__ W, __hip_bfloat16* __restrict__ Wb) {
  const size_t row = blockIdx.x;
  float* p = W + row * (size_t)Ss;
  __hip_bfloat16* pb = Wb + row * (size_t)Ss;
  const int tid = threadIdx.x;
  __shared__ float red[4];

  const float4* p4 = (const float4*)p;
  const float4 a = p4[2 * tid];
  const float4 bq = p4[2 * tid + 1];
  float v[8] = {a.x, a.y, a.z, a.w, bq.x, bq.y, bq.z, bq.w};

  float m = v[0];
#pragma unroll
  for (int e = 1; e < 8; ++e) m = fmaxf(m, v[e]);
#pragma unroll
  for (int off = 32; off > 0; off >>= 1) m = fmaxf(m, __shfl_xor(m, off, 64));
  if ((tid & 63) == 0) red[tid >> 6] = m;
  __syncthreads();
  m = fmaxf(fmaxf(red[0], red[1]), fmaxf(red[2], red[3]));

  float sum = 0.0f;
#pragma unroll
  for (int e = 0; e < 8; ++e) { v[e] = __expf(v[e] - m); sum += v[e]; }
#pragma unroll
  for (int off = 32; off > 0; off >>= 1) sum += __shfl_xor(sum, off, 64);
  __syncthreads();                  // red reads done before overwrite
  if ((tid & 63) == 0) red[tid >> 6] = sum;
  __syncthreads();
  sum = red[0] + red[1] + red[2] + red[3];

  const float rs = 1.0f / sum;
#pragma unroll
  for (int e = 0; e < 8; ++e) v[e] *= rs;

  float4* o4 = (float4*)p;
  o4[2 * tid]     = make_float4(v[0], v[1], v[2], v[3]);
  o4[2 * tid + 1] = make_float4(v[4], v[5], v[6], v[7]);

  bf16x8 ob;
#pragma unroll
  for (int e = 0; e < 8; ++e) ob[e] = (short)bf16bits(v[e]);
  *(bf16x8*)&pb[8 * tid] = ob;
}

// ---------------------------------------------------------------------------
extern "C" void kernel_launch(void* const* d_in, const int* in_sizes, int n_in,
                              void* d_out, int out_size, void* d_ws, size_t ws_size,
                              hipStream_t stream) {
  const float* Q = (const float*)d_in[0];
  const float* K = (const float*)d_in[1];
  const float* V = (const float*)d_in[2];

  float* out     = (float*)d_out;                       // [B,S,H]
  float* weights = out + (size_t)Bb * Ss * Hh;          // [B,S,S]

  __hip_bfloat16* FQb = (__hip_bfloat16*)d_ws;
  __hip_bfloat16* FKb = FQb + (size_t)Bb * Ss * KP2;
  __hip_bfloat16* Vtb = FKb + (size_t)Bb * Ss * KP2;
  __hip_bfloat16* Wb  = (__hip_bfloat16*)d_ws;          // aliases dead FQb/FKb

  hipLaunchKernelGGL(fft_phase_kernel, dim3(Bb * Ss), dim3(256), 0, stream,
                     Q, K, FQb, FKb);
  hipLaunchKernelGGL(vt_kernel, dim3(Hh / 32, Ss / 32, Bb), dim3(256), 0, stream,
                     V, Vtb);
  hipLaunchKernelGGL((gemm_bt<KP2, KP2, KP2, Ss, 0>), dim3(16, 16, Bb), dim3(256), 0, stream,
                     FQb, FKb, weights,
                     (size_t)Ss * KP2, (size_t)Ss * KP2, (size_t)Ss * Ss);
  hipLaunchKernelGGL(softmax_kernel, dim3(Bb * Ss), dim3(256), 0, stream,
                     weights, Wb);
  hipLaunchKernelGGL((gemm_bt<Ss, Ss, Ss, Hh, 1>), dim3(8, 16, Bb), dim3(256), 0, stream,
                     Wb, Vtb, out,
                     (size_t)Ss * Ss, (size_t)Hh * Ss, (size_t)Ss * Hh);
}

// Round 5
// 197.435 us; speedup vs baseline: 1.0648x; 1.0648x over previous
//
#include <hip/hip_runtime.h>
#include <hip/hip_bf16.h>
#include <math.h>

// Problem constants
#define Bb 4
#define Ss 2048
#define Hh 1024
#define Ff 513           // H/2 + 1 rfft bins
#define FEAT 1026        // cos||sin feature length
#define KP2 1088         // padded feature K (17 * 64)

typedef __attribute__((ext_vector_type(8))) short bf16x8;
typedef __attribute__((ext_vector_type(4))) float f32x4;

typedef const __attribute__((address_space(1))) void GVoid;
typedef __attribute__((address_space(3))) void LVoid;

// padded LDS index for float2 arrays: breaks power-of-2 stride conflicts
#define PADI(i) ((i) + ((i) >> 4))

__device__ __forceinline__ float2 cmul(float2 a, float2 b) {
  return make_float2(a.x * b.x - a.y * b.y, a.x * b.y + a.y * b.x);
}

__device__ __forceinline__ unsigned short bf16bits(float x) {
  __hip_bfloat16 h = __float2bfloat16(x);
  return *reinterpret_cast<unsigned short*>(&h);
}

// raw workgroup barrier WITHOUT vmcnt drain (memory clobber = compiler fence)
__device__ __forceinline__ void wgbar() { asm volatile("s_barrier" ::: "memory"); }

// ---------------------------------------------------------------------------
// Kernel 1: packed-real FFT. One block per (b,s) row-pair: z = Q_row + i*K_row,
// single 1024-pt radix-4 DIT FFT (5 stages), untangle, unit-normalize,
// emit bf16 [cos||sin] features.
// ---------------------------------------------------------------------------
__global__ __launch_bounds__(256) void fft_phase_kernel(
    const float* __restrict__ Q, const float* __restrict__ Kin,
    __hip_bfloat16* __restrict__ FQ, __hip_bfloat16* __restrict__ FK) {
  const int row = blockIdx.x;                     // 0 .. B*S-1
  const float* qs = Q   + (size_t)row * Hh;
  const float* ks = Kin + (size_t)row * Hh;
  __hip_bfloat16* fq = FQ + (size_t)row * KP2;
  __hip_bfloat16* fk = FK + (size_t)row * KP2;

  __shared__ float2 data[PADI(1023) + 1];
  __shared__ float2 tw[1024];
  const int tid = threadIdx.x;

#pragma unroll
  for (int e = 0; e < 4; ++e) {
    const int m = tid + e * 256;
    float s, c;
    sincosf(-6.283185307179586f * (float)m * (1.0f / 1024.0f), &s, &c);
    tw[m] = make_float2(c, s);
  }
#pragma unroll
  for (int e = 0; e < 4; ++e) {
    const int n = tid + e * 256;
    const int r4 = ((n & 3) << 8) | (((n >> 2) & 3) << 6) | (((n >> 4) & 3) << 4)
                 | (((n >> 6) & 3) << 2) | ((n >> 8) & 3);
    data[PADI(r4)] = make_float2(qs[n], ks[n]);
  }
  __syncthreads();

  int quarter = 1, step = 256;
  for (int s = 0; s < 5; ++s) {
    const int j = tid & (quarter - 1);
    const int pos = 4 * tid - 3 * j;
    const float2 x0 = data[PADI(pos)];
    const float2 x1 = data[PADI(pos + quarter)];
    const float2 x2 = data[PADI(pos + 2 * quarter)];
    const float2 x3 = data[PADI(pos + 3 * quarter)];
    const int e1 = j * step;
    const float2 a1 = cmul(x1, tw[e1]);
    const float2 a2 = cmul(x2, tw[2 * e1]);
    const float2 a3 = cmul(x3, tw[3 * e1]);
    const float2 t0 = make_float2(x0.x + a2.x, x0.y + a2.y);
    const float2 t1 = make_float2(x0.x - a2.x, x0.y - a2.y);
    const float2 t2 = make_float2(a1.x + a3.x, a1.y + a3.y);
    const float2 t3 = make_float2(a1.x - a3.x, a1.y - a3.y);
    data[PADI(pos)]               = make_float2(t0.x + t2.x, t0.y + t2.y);
    data[PADI(pos + quarter)]     = make_float2(t1.x + t3.y, t1.y - t3.x);
    data[PADI(pos + 2 * quarter)] = make_float2(t0.x - t2.x, t0.y - t2.y);
    data[PADI(pos + 3 * quarter)] = make_float2(t1.x - t3.y, t1.y + t3.x);
    __syncthreads();
    quarter <<= 2; step >>= 2;
  }

  for (int f = tid; f <= 512; f += 256) {
    const float2 z1 = data[PADI(f)];
    const float2 z2 = data[PADI((1024 - f) & 1023)];
    const float qr = z1.x + z2.x, qi = z1.y - z2.y;
    const float kr = z1.y + z2.y, ki = z2.x - z1.x;
    float qc, qsn, kc, ksn;
    const float qm2 = qr * qr + qi * qi;
    if (qm2 > 1e-30f) { const float iv = rsqrtf(qm2); qc = qr * iv; qsn = qi * iv; }
    else              { qc = 1.0f; qsn = 0.0f; }
    const float km2 = kr * kr + ki * ki;
    if (km2 > 1e-30f) { const float iv = rsqrtf(km2); kc = kr * iv; ksn = ki * iv; }
    else              { kc = 1.0f; ksn = 0.0f; }
    fq[f] = __float2bfloat16(qc); fq[Ff + f] = __float2bfloat16(qsn);
    fk[f] = __float2bfloat16(kc); fk[Ff + f] = __float2bfloat16(ksn);
  }
  for (int p = FEAT + tid; p < KP2; p += 256) {
    fq[p] = __float2bfloat16(0.0f);
    fk[p] = __float2bfloat16(0.0f);
  }
}

// ---------------------------------------------------------------------------
// Kernel 2: V [B,S,H] fp32 -> Vt [B,H,S] bf16 (transpose, LDS 32x33 tile)
// ---------------------------------------------------------------------------
__global__ __launch_bounds__(256) void vt_kernel(
    const float* __restrict__ V, __hip_bfloat16* __restrict__ Vt) {
  const int b = blockIdx.z;
  const int h0 = blockIdx.x * 32;
  const int s0 = blockIdx.y * 32;
  __shared__ float t[32][33];
  const int tid = threadIdx.x;
  const int c = tid & 31;
  const int r8 = tid >> 5;
  const float* Vb = V + (size_t)b * Ss * Hh;
#pragma unroll
  for (int e = 0; e < 4; ++e) {
    const int r = r8 + e * 8;
    t[r][c] = Vb[(size_t)(s0 + r) * Hh + h0 + c];
  }
  __syncthreads();
  __hip_bfloat16* O = Vt + (size_t)b * Hh * Ss;
#pragma unroll
  for (int e = 0; e < 4; ++e) {
    const int hh = r8 + e * 8;
    O[(size_t)(h0 + hh) * Ss + s0 + c] = __float2bfloat16(t[c][hh]);
  }
}

// ---------------------------------------------------------------------------
// bf16 MFMA GEMM, C = A * B^T, 256x256 tile, BK=64, 8 waves (2M x 4N),
// phase-split schedule (T3+T4+T5): 4 phases per K-tile, each phase
// { ds_read frags | issue one stage chunk | s_barrier | MFMA(setprio) |
//   [vmcnt(6) at phase 3] | s_barrier }.
// LDS layout per buffer: [16 row-group][2 khalf][4 kchunk][16 row][8 bf16];
// global_load_lds lane order == fragment read order -> conflict-free,
// no swizzle needed. Stage chunk = (matrix, khalf) = 2 loads/thread.
// Chunk lifetimes (consumed by end of): B-kh0: ph0, A-kh0: ph1,
// B-kh1: ph2, A-kh1: ph3 -> stage schedule: ph0: A-kh1(t+1)->buf^1,
// ph1: B-kh0(t+2), ph2: A-kh0(t+2), ph3: B-kh1(t+2) (into current buf,
// regions already consumed this tile). vmcnt(6) at ph3 = this tile's
// ph1-3 stages stay in flight; everything older (all of t+1) landed.
// EPI 0: C = acc/513 (scores). EPI 1: C = acc (PV).
// ---------------------------------------------------------------------------
template<int K, int LDA, int LDB, int LDC, int EPI>
__global__ __launch_bounds__(512, 2) void gemm256(
    const __hip_bfloat16* __restrict__ Ag, const __hip_bfloat16* __restrict__ Bg,
    float* __restrict__ Cg, size_t strA, size_t strB, size_t strC) {
  constexpr int nt = K / 64;
  const int b = blockIdx.z;
  const int i0 = blockIdx.y * 256;
  const int j0 = blockIdx.x * 256;
  const char* Ab = (const char*)(Ag + (size_t)b * strA);
  const char* Bp = (const char*)(Bg + (size_t)b * strB);
  float* C = Cg + (size_t)b * strC;

  __shared__ short As[2][16384];   // 2 x 32KB
  __shared__ short Bs[2][16384];   // 2 x 32KB   (total 128KB)

  const int tid = threadIdx.x;
  const int lane = tid & 63;
  const int w  = tid >> 6;        // wave 0..7
  const int wm = w >> 2;          // 0..1 (M)
  const int wn = w & 3;           // 0..3 (N)
  const int lr = lane & 15;
  const int lc = lane >> 4;

  f32x4 acc[8][4];
#pragma unroll
  for (int m = 0; m < 8; ++m)
#pragma unroll
    for (int n = 0; n < 4; ++n)
      acc[m][n] = (f32x4){0.0f, 0.0f, 0.0f, 0.0f};

  // stage chunk (matrix, khalf) of K-tile tt into buffer dd: 2 loads/thread
#define SA(dd, tt, kh)                                                                   \
  do {                                                                                   \
    _Pragma("unroll")                                                                    \
    for (int ii = 0; ii < 2; ++ii) {                                                     \
      const int g = w * 2 + ii;                                                          \
      __builtin_amdgcn_global_load_lds(                                                  \
          (GVoid*)(Ab + (size_t)(i0 + g * 16 + lr) * (LDA * 2) + (size_t)(tt) * 128 +    \
                   (kh) * 64 + lc * 16),                                                 \
          (LVoid*)&As[dd][(g * 2 + (kh)) * 512], 16, 0, 0);                              \
    }                                                                                    \
  } while (0)
#define SB(dd, tt, kh)                                                                   \
  do {                                                                                   \
    _Pragma("unroll")                                                                    \
    for (int ii = 0; ii < 2; ++ii) {                                                     \
      const int g = w * 2 + ii;                                                          \
      __builtin_amdgcn_global_load_lds(                                                  \
          (GVoid*)(Bp + (size_t)(j0 + g * 16 + lr) * (LDB * 2) + (size_t)(tt) * 128 +    \
                   (kh) * 64 + lc * 16),                                                 \
          (LVoid*)&Bs[dd][(g * 2 + (kh)) * 512], 16, 0, 0);                              \
    }                                                                                    \
  } while (0)
  // read 4 A-frags (m-half mh, khalf kh) / 4 B-frags (khalf kh)
#define RA(dd, mh, kh)                                                                   \
  _Pragma("unroll")                                                                      \
  for (int mi = 0; mi < 4; ++mi)                                                         \
    af[mi] = *(const bf16x8*)&As[dd][(((wm * 8 + (mh) * 4 + mi) * 2 + (kh)) * 4 + lc) * 128 + lr * 8];
#define RB(dd, kh)                                                                       \
  _Pragma("unroll")                                                                      \
  for (int ni = 0; ni < 4; ++ni)                                                         \
    bf[ni] = *(const bf16x8*)&Bs[dd][(((wn * 4 + ni) * 2 + (kh)) * 4 + lc) * 128 + lr * 8];
#define MM(mh)                                                                           \
  __builtin_amdgcn_s_setprio(1);                                                         \
  _Pragma("unroll")                                                                      \
  for (int mi = 0; mi < 4; ++mi)                                                         \
    _Pragma("unroll")                                                                    \
    for (int ni = 0; ni < 4; ++ni)                                                       \
      acc[(mh) * 4 + mi][ni] =                                                           \
          __builtin_amdgcn_mfma_f32_16x16x32_bf16(af[mi], bf[ni], acc[(mh) * 4 + mi][ni], 0, 0, 0); \
  __builtin_amdgcn_s_setprio(0);

  // prologue: stage tiles 0 and 1 fully; wait tile 0 (8 newer may remain)
  SA(0, 0, 0); SA(0, 0, 1); SB(0, 0, 0); SB(0, 0, 1);
  SA(1, 1, 0); SA(1, 1, 1); SB(1, 1, 0); SB(1, 1, 1);
  asm volatile("s_waitcnt vmcnt(8)" ::: "memory");
  wgbar();

  for (int t = 0; t < nt; ++t) {
    const int d = t & 1;
    bf16x8 af[4], bf[4];

    // ---- phase 0: kh0, m-half 0
    RA(d, 0, 0); RB(d, 0);
    if (t >= 1 && t + 1 < nt) SA(d ^ 1, t + 1, 1);
    wgbar();
    MM(0);
    wgbar();

    // ---- phase 1: kh0, m-half 1 (reuse bf)
    RA(d, 1, 0);
    if (t + 2 < nt) SB(d, t + 2, 0);
    wgbar();
    MM(1);
    wgbar();

    // ---- phase 2: kh1, m-half 0
    RA(d, 0, 1); RB(d, 1);
    if (t + 2 < nt) SA(d, t + 2, 0);
    wgbar();
    MM(0);
    wgbar();

    // ---- phase 3: kh1, m-half 1 (reuse bf)
    RA(d, 1, 1);
    if (t + 2 < nt) SB(d, t + 2, 1);
    wgbar();
    MM(1);
    if (t + 2 < nt) asm volatile("s_waitcnt vmcnt(6)" ::: "memory");
    else            asm volatile("s_waitcnt vmcnt(0)" ::: "memory");
    wgbar();
  }
#undef SA
#undef SB
#undef RA
#undef RB
#undef MM

  // epilogue: C/D layout col = lane&15, row = (lane>>4)*4 + reg  [m89]
#pragma unroll
  for (int m = 0; m < 8; ++m) {
    const int ib = i0 + wm * 128 + m * 16 + lc * 4;
#pragma unroll
    for (int n = 0; n < 4; ++n) {
      const int j = j0 + wn * 64 + n * 16 + lr;
#pragma unroll
      for (int r = 0; r < 4; ++r) {
        float v = acc[m][n][r];
        if (EPI == 0) v = v * (1.0f / 513.0f);
        C[(size_t)(ib + r) * LDC + j] = v;
      }
    }
  }
}

// ---------------------------------------------------------------------------
// Kernel 3: in-place row softmax over 2048 cols + bf16 copy for PV GEMM.
// ---------------------------------------------------------------------------
__global__ __launch_bounds__(256) void softmax_kernel(
    float* __restrict__ W, __hip_bfloat16* __restrict__ Wb) {
  const size_t row = blockIdx.x;
  float* p = W + row * (size_t)Ss;
  __hip_bfloat16* pb = Wb + row * (size_t)Ss;
  const int tid = threadIdx.x;
  __shared__ float red[4];

  const float4* p4 = (const float4*)p;
  const float4 a = p4[2 * tid];
  const float4 bq = p4[2 * tid + 1];
  float v[8] = {a.x, a.y, a.z, a.w, bq.x, bq.y, bq.z, bq.w};

  float m = v[0];
#pragma unroll
  for (int e = 1; e < 8; ++e) m = fmaxf(m, v[e]);
#pragma unroll
  for (int off = 32; off > 0; off >>= 1) m = fmaxf(m, __shfl_xor(m, off, 64));
  if ((tid & 63) == 0) red[tid >> 6] = m;
  __syncthreads();
  m = fmaxf(fmaxf(red[0], red[1]), fmaxf(red[2], red[3]));

  float sum = 0.0f;
#pragma unroll
  for (int e = 0; e < 8; ++e) { v[e] = __expf(v[e] - m); sum += v[e]; }
#pragma unroll
  for (int off = 32; off > 0; off >>= 1) sum += __shfl_xor(sum, off, 64);
  __syncthreads();
  if ((tid & 63) == 0) red[tid >> 6] = sum;
  __syncthreads();
  sum = red[0] + red[1] + red[2] + red[3];

  const float rs = 1.0f / sum;
#pragma unroll
  for (int e = 0; e < 8; ++e) v[e] *= rs;

  float4* o4 = (float4*)p;
  o4[2 * tid]     = make_float4(v[0], v[1], v[2], v[3]);
  o4[2 * tid + 1] = make_float4(v[4], v[5], v[6], v[7]);

  bf16x8 ob;
#pragma unroll
  for (int e = 0; e < 8; ++e) ob[e] = (short)bf16bits(v[e]);
  *(bf16x8*)&pb[8 * tid] = ob;
}

// ---------------------------------------------------------------------------
extern "C" void kernel_launch(void* const* d_in, const int* in_sizes, int n_in,
                              void* d_out, int out_size, void* d_ws, size_t ws_size,
                              hipStream_t stream) {
  const float* Q = (const float*)d_in[0];
  const float* K = (const float*)d_in[1];
  const float* V = (const float*)d_in[2];

  float* out     = (float*)d_out;                       // [B,S,H]
  float* weights = out + (size_t)Bb * Ss * Hh;          // [B,S,S]

  __hip_bfloat16* FQb = (__hip_bfloat16*)d_ws;
  __hip_bfloat16* FKb = FQb + (size_t)Bb * Ss * KP2;
  __hip_bfloat16* Vtb = FKb + (size_t)Bb * Ss * KP2;
  __hip_bfloat16* Wb  = (__hip_bfloat16*)d_ws;          // aliases dead FQb/FKb

  hipLaunchKernelGGL(fft_phase_kernel, dim3(Bb * Ss), dim3(256), 0, stream,
                     Q, K, FQb, FKb);
  hipLaunchKernelGGL(vt_kernel, dim3(Hh / 32, Ss / 32, Bb), dim3(256), 0, stream,
                     V, Vtb);
  hipLaunchKernelGGL((gemm256<KP2, KP2, KP2, Ss, 0>), dim3(Ss / 256, Ss / 256, Bb),
                     dim3(512), 0, stream, FQb, FKb, weights,
                     (size_t)Ss * KP2, (size_t)Ss * KP2, (size_t)Ss * Ss);
  hipLaunchKernelGGL(softmax_kernel, dim3(Bb * Ss), dim3(256), 0, stream,
                     weights, Wb);
  hipLaunchKernelGGL((gemm256<Ss, Ss, Ss, Hh, 1>), dim3(Hh / 256, Ss / 256, Bb),
                     dim3(512), 0, stream, Wb, Vtb, out,
                     (size_t)Ss * Ss, (size_t)Hh * Ss, (size_t)Ss * Hh);
}

// Round 6
// 169.609 us; speedup vs baseline: 1.2395x; 1.1641x over previous
//
#include <hip/hip_runtime.h>
#include <hip/hip_bf16.h>
#include <math.h>

// Problem constants
#define Bb 4
#define Ss 2048
#define Hh 1024
#define Ff 513           // H/2 + 1 rfft bins
#define FEAT 1026        // cos||sin feature length
#define KP2 1088         // padded feature K (17 * 64)

typedef __attribute__((ext_vector_type(8))) short bf16x8;
typedef __attribute__((ext_vector_type(4))) float f32x4;

typedef const __attribute__((address_space(1))) void GVoid;
typedef __attribute__((address_space(3))) void LVoid;

// padded LDS index for float2 arrays: breaks power-of-2 stride conflicts
#define PADI(i) ((i) + ((i) >> 4))

__device__ __forceinline__ float2 cmul(float2 a, float2 b) {
  return make_float2(a.x * b.x - a.y * b.y, a.x * b.y + a.y * b.x);
}

__device__ __forceinline__ unsigned short bf16bits(float x) {
  __hip_bfloat16 h = __float2bfloat16(x);
  return *reinterpret_cast<unsigned short*>(&h);
}

// Inline-asm LDS read: opaque to the compiler's waitcnt insertion, so the
// counted-vmcnt pipeline is not silently drained (round-5 post-mortem).
// Ordering is enforced manually: s_waitcnt lgkmcnt(0) + sched_barrier(0)
// before the MFMA cluster (rule #18), barriers around phases.
__device__ __forceinline__ bf16x8 lds_read_b128(const short* p) {
  bf16x8 r;
  asm volatile("ds_read_b128 %0, %1"
               : "=&v"(r)
               : "v"((const __attribute__((address_space(3))) short*)p));
  return r;
}

// ---------------------------------------------------------------------------
// Kernel 1: packed-real FFT. One block per (b,s) row-pair: z = Q_row + i*K_row,
// single 1024-pt radix-4 DIT FFT (5 stages), untangle, unit-normalize,
// emit bf16 [cos||sin] features.
// ---------------------------------------------------------------------------
__global__ __launch_bounds__(256) void fft_phase_kernel(
    const float* __restrict__ Q, const float* __restrict__ Kin,
    __hip_bfloat16* __restrict__ FQ, __hip_bfloat16* __restrict__ FK) {
  const int row = blockIdx.x;                     // 0 .. B*S-1
  const float* qs = Q   + (size_t)row * Hh;
  const float* ks = Kin + (size_t)row * Hh;
  __hip_bfloat16* fq = FQ + (size_t)row * KP2;
  __hip_bfloat16* fk = FK + (size_t)row * KP2;

  __shared__ float2 data[PADI(1023) + 1];
  __shared__ float2 tw[1024];
  const int tid = threadIdx.x;

#pragma unroll
  for (int e = 0; e < 4; ++e) {
    const int m = tid + e * 256;
    float s, c;
    sincosf(-6.283185307179586f * (float)m * (1.0f / 1024.0f), &s, &c);
    tw[m] = make_float2(c, s);
  }
#pragma unroll
  for (int e = 0; e < 4; ++e) {
    const int n = tid + e * 256;
    const int r4 = ((n & 3) << 8) | (((n >> 2) & 3) << 6) | (((n >> 4) & 3) << 4)
                 | (((n >> 6) & 3) << 2) | ((n >> 8) & 3);
    data[PADI(r4)] = make_float2(qs[n], ks[n]);
  }
  __syncthreads();

  int quarter = 1, step = 256;
  for (int s = 0; s < 5; ++s) {
    const int j = tid & (quarter - 1);
    const int pos = 4 * tid - 3 * j;
    const float2 x0 = data[PADI(pos)];
    const float2 x1 = data[PADI(pos + quarter)];
    const float2 x2 = data[PADI(pos + 2 * quarter)];
    const float2 x3 = data[PADI(pos + 3 * quarter)];
    const int e1 = j * step;
    const float2 a1 = cmul(x1, tw[e1]);
    const float2 a2 = cmul(x2, tw[2 * e1]);
    const float2 a3 = cmul(x3, tw[3 * e1]);
    const float2 t0 = make_float2(x0.x + a2.x, x0.y + a2.y);
    const float2 t1 = make_float2(x0.x - a2.x, x0.y - a2.y);
    const float2 t2 = make_float2(a1.x + a3.x, a1.y + a3.y);
    const float2 t3 = make_float2(a1.x - a3.x, a1.y - a3.y);
    data[PADI(pos)]               = make_float2(t0.x + t2.x, t0.y + t2.y);
    data[PADI(pos + quarter)]     = make_float2(t1.x + t3.y, t1.y - t3.x);
    data[PADI(pos + 2 * quarter)] = make_float2(t0.x - t2.x, t0.y - t2.y);
    data[PADI(pos + 3 * quarter)] = make_float2(t1.x - t3.y, t1.y + t3.x);
    __syncthreads();
    quarter <<= 2; step >>= 2;
  }

  for (int f = tid; f <= 512; f += 256) {
    const float2 z1 = data[PADI(f)];
    const float2 z2 = data[PADI((1024 - f) & 1023)];
    const float qr = z1.x + z2.x, qi = z1.y - z2.y;
    const float kr = z1.y + z2.y, ki = z2.x - z1.x;
    float qc, qsn, kc, ksn;
    const float qm2 = qr * qr + qi * qi;
    if (qm2 > 1e-30f) { const float iv = rsqrtf(qm2); qc = qr * iv; qsn = qi * iv; }
    else              { qc = 1.0f; qsn = 0.0f; }
    const float km2 = kr * kr + ki * ki;
    if (km2 > 1e-30f) { const float iv = rsqrtf(km2); kc = kr * iv; ksn = ki * iv; }
    else              { kc = 1.0f; ksn = 0.0f; }
    fq[f] = __float2bfloat16(qc); fq[Ff + f] = __float2bfloat16(qsn);
    fk[f] = __float2bfloat16(kc); fk[Ff + f] = __float2bfloat16(ksn);
  }
  for (int p = FEAT + tid; p < KP2; p += 256) {
    fq[p] = __float2bfloat16(0.0f);
    fk[p] = __float2bfloat16(0.0f);
  }
}

// ---------------------------------------------------------------------------
// Kernel 2: V [B,S,H] fp32 -> Vt [B,H,S] bf16 (transpose, LDS 32x33 tile)
// ---------------------------------------------------------------------------
__global__ __launch_bounds__(256) void vt_kernel(
    const float* __restrict__ V, __hip_bfloat16* __restrict__ Vt) {
  const int b = blockIdx.z;
  const int h0 = blockIdx.x * 32;
  const int s0 = blockIdx.y * 32;
  __shared__ float t[32][33];
  const int tid = threadIdx.x;
  const int c = tid & 31;
  const int r8 = tid >> 5;
  const float* Vb = V + (size_t)b * Ss * Hh;
#pragma unroll
  for (int e = 0; e < 4; ++e) {
    const int r = r8 + e * 8;
    t[r][c] = Vb[(size_t)(s0 + r) * Hh + h0 + c];
  }
  __syncthreads();
  __hip_bfloat16* O = Vt + (size_t)b * Hh * Ss;
#pragma unroll
  for (int e = 0; e < 4; ++e) {
    const int hh = r8 + e * 8;
    O[(size_t)(h0 + hh) * Ss + s0 + c] = __float2bfloat16(t[c][hh]);
  }
}

// ---------------------------------------------------------------------------
// bf16 MFMA GEMM, C = A * B^T, 256 x BNT tile, BK=64, 8 waves (2M x 4N),
// 4 phases per K-tile with counted vmcnt (T3+T4) + setprio (T5).
// LDS frag reads are inline-asm ds_read_b128 (opaque to compiler waitcnt
// insertion); explicit lgkmcnt(0)+sched_barrier(0) before each MFMA cluster
// (rule #18); raw s_barrier builtin (no implicit vmcnt drain).
// Race-freedom: each chunk's overwrite is issued >= 1 barrier after its last
// reader phase's lgkmcnt(0)+MFMA+barrier; buffer-ready is guaranteed by the
// once-per-tile counted vmcnt + barrier. BNT=256 (LB=2): steady vmcnt(6);
// BNT=128 (LB=1): steady vmcnt(4).
// EPI 0: C = acc/513 (scores). EPI 1: C = acc (PV).
// ---------------------------------------------------------------------------
template<int K, int LDA, int LDB, int LDC, int EPI, int BNT>
__global__ __launch_bounds__(512, 2) void gemm256(
    const __hip_bfloat16* __restrict__ Ag, const __hip_bfloat16* __restrict__ Bg,
    float* __restrict__ Cg, size_t strA, size_t strB, size_t strC) {
  constexpr int nt = K / 64;
  constexpr int NW = BNT / 64;    // B-frags per wave per khalf
  constexpr int LB = BNT / 128;   // loads/thread per SB chunk
  const int b = blockIdx.z;
  const int i0 = blockIdx.y * 256;
  const int j0 = blockIdx.x * BNT;
  const char* Ab = (const char*)(Ag + (size_t)b * strA);
  const char* Bp = (const char*)(Bg + (size_t)b * strB);
  float* C = Cg + (size_t)b * strC;

  __shared__ short As[2][16384];      // 2 x 32KB
  __shared__ short Bs[2][BNT * 64];   // 2 x (BNT/256 * 32KB)

  const int tid = threadIdx.x;
  const int lane = tid & 63;
  const int w  = tid >> 6;        // wave 0..7
  const int wm = w >> 2;          // 0..1 (M)
  const int wn = w & 3;           // 0..3 (N)
  const int lr = lane & 15;
  const int lc = lane >> 4;

  f32x4 acc[8][NW];
#pragma unroll
  for (int m = 0; m < 8; ++m)
#pragma unroll
    for (int n = 0; n < NW; ++n)
      acc[m][n] = (f32x4){0.0f, 0.0f, 0.0f, 0.0f};

#define BAR() __builtin_amdgcn_s_barrier()

  // stage chunk (matrix, khalf) of K-tile tt into buffer dd
#define SA(dd, tt, kh)                                                                   \
  do {                                                                                   \
    _Pragma("unroll")                                                                    \
    for (int ii = 0; ii < 2; ++ii) {                                                     \
      const int g = w * 2 + ii;                                                          \
      __builtin_amdgcn_global_load_lds(                                                  \
          (GVoid*)(Ab + (size_t)(i0 + g * 16 + lr) * (LDA * 2) + (size_t)(tt) * 128 +    \
                   (kh) * 64 + lc * 16),                                                 \
          (LVoid*)&As[dd][(g * 2 + (kh)) * 512], 16, 0, 0);                              \
    }                                                                                    \
  } while (0)
#define SB(dd, tt, kh)                                                                   \
  do {                                                                                   \
    _Pragma("unroll")                                                                    \
    for (int ii = 0; ii < LB; ++ii) {                                                    \
      const int g = w * LB + ii;                                                         \
      __builtin_amdgcn_global_load_lds(                                                  \
          (GVoid*)(Bp + (size_t)(j0 + g * 16 + lr) * (LDB * 2) + (size_t)(tt) * 128 +    \
                   (kh) * 64 + lc * 16),                                                 \
          (LVoid*)&Bs[dd][(g * 2 + (kh)) * 512], 16, 0, 0);                              \
    }                                                                                    \
  } while (0)
  // read A-frags (m-half mh, khalf kh) / B-frags (khalf kh) via asm ds_read
#define RA(dd, mh, kh)                                                                   \
  _Pragma("unroll")                                                                      \
  for (int mi = 0; mi < 4; ++mi)                                                         \
    af[mi] = lds_read_b128(                                                              \
        &As[dd][(((wm * 8 + (mh) * 4 + mi) * 2 + (kh)) * 4 + lc) * 128 + lr * 8]);
#define RB(dd, kh)                                                                       \
  _Pragma("unroll")                                                                      \
  for (int ni = 0; ni < NW; ++ni)                                                        \
    bf[ni] = lds_read_b128(                                                              \
        &Bs[dd][(((wn * NW + ni) * 2 + (kh)) * 4 + lc) * 128 + lr * 8]);
#define MM(mh)                                                                           \
  asm volatile("s_waitcnt lgkmcnt(0)");                                                  \
  __builtin_amdgcn_sched_barrier(0);                                                     \
  __builtin_amdgcn_s_setprio(1);                                                         \
  _Pragma("unroll")                                                                      \
  for (int mi = 0; mi < 4; ++mi)                                                         \
    _Pragma("unroll")                                                                    \
    for (int ni = 0; ni < NW; ++ni)                                                      \
      acc[(mh) * 4 + mi][ni] =                                                           \
          __builtin_amdgcn_mfma_f32_16x16x32_bf16(af[mi], bf[ni], acc[(mh) * 4 + mi][ni], 0, 0, 0); \
  __builtin_amdgcn_s_setprio(0);                                                         \
  __builtin_amdgcn_sched_barrier(0);

  // prologue: stage tiles 0 and 1 fully; wait until only tile-1's loads remain
  SA(0, 0, 0); SA(0, 0, 1); SB(0, 0, 0); SB(0, 0, 1);
  SA(1, 1, 0); SA(1, 1, 1); SB(1, 1, 0); SB(1, 1, 1);
  if constexpr (LB == 2) asm volatile("s_waitcnt vmcnt(8)");
  else                   asm volatile("s_waitcnt vmcnt(6)");
  BAR();

  for (int t = 0; t < nt; ++t) {
    const int d = t & 1;
    bf16x8 af[4], bf[NW];

    // ---- phase 0: kh0, m-half 0
    RA(d, 0, 0); RB(d, 0);
    if (t >= 1 && t + 1 < nt) SA(d ^ 1, t + 1, 1);
    BAR();
    MM(0);
    BAR();

    // ---- phase 1: kh0, m-half 1 (reuse bf)
    RA(d, 1, 0);
    if (t + 2 < nt) SB(d, t + 2, 0);
    BAR();
    MM(1);
    BAR();

    // ---- phase 2: kh1, m-half 0
    RA(d, 0, 1); RB(d, 1);
    if (t + 2 < nt) SA(d, t + 2, 0);
    BAR();
    MM(0);
    BAR();

    // ---- phase 3: kh1, m-half 1 (reuse bf)
    RA(d, 1, 1);
    if (t + 2 < nt) SB(d, t + 2, 1);
    BAR();
    MM(1);
    if (t + 2 < nt) {
      if constexpr (LB == 2) asm volatile("s_waitcnt vmcnt(6)");
      else                   asm volatile("s_waitcnt vmcnt(4)");
    } else {
      asm volatile("s_waitcnt vmcnt(0)");
    }
    BAR();
  }
#undef SA
#undef SB
#undef RA
#undef RB
#undef MM
#undef BAR

  // epilogue: C/D layout col = lane&15, row = (lane>>4)*4 + reg  [m89]
#pragma unroll
  for (int m = 0; m < 8; ++m) {
    const int ib = i0 + wm * 128 + m * 16 + lc * 4;
#pragma unroll
    for (int n = 0; n < NW; ++n) {
      const int j = j0 + wn * (BNT / 4) + n * 16 + lr;
#pragma unroll
      for (int r = 0; r < 4; ++r) {
        float v = acc[m][n][r];
        if (EPI == 0) v = v * (1.0f / 513.0f);
        C[(size_t)(ib + r) * LDC + j] = v;
      }
    }
  }
}

// ---------------------------------------------------------------------------
// Kernel 3: in-place row softmax over 2048 cols + bf16 copy for PV GEMM.
// ---------------------------------------------------------------------------
__global__ __launch_bounds__(256) void softmax_kernel(
    float* __restrict__ W, __hip_bfloat16* __restrict__ Wb) {
  const size_t row = blockIdx.x;
  float* p = W + row * (size_t)Ss;
  __hip_bfloat16* pb = Wb + row * (size_t)Ss;
  const int tid = threadIdx.x;
  __shared__ float red[4];

  const float4* p4 = (const float4*)p;
  const float4 a = p4[2 * tid];
  const float4 bq = p4[2 * tid + 1];
  float v[8] = {a.x, a.y, a.z, a.w, bq.x, bq.y, bq.z, bq.w};

  float m = v[0];
#pragma unroll
  for (int e = 1; e < 8; ++e) m = fmaxf(m, v[e]);
#pragma unroll
  for (int off = 32; off > 0; off >>= 1) m = fmaxf(m, __shfl_xor(m, off, 64));
  if ((tid & 63) == 0) red[tid >> 6] = m;
  __syncthreads();
  m = fmaxf(fmaxf(red[0], red[1]), fmaxf(red[2], red[3]));

  float sum = 0.0f;
#pragma unroll
  for (int e = 0; e < 8; ++e) { v[e] = __expf(v[e] - m); sum += v[e]; }
#pragma unroll
  for (int off = 32; off > 0; off >>= 1) sum += __shfl_xor(sum, off, 64);
  __syncthreads();
  if ((tid & 63) == 0) red[tid >> 6] = sum;
  __syncthreads();
  sum = red[0] + red[1] + red[2] + red[3];

  const float rs = 1.0f / sum;
#pragma unroll
  for (int e = 0; e < 8; ++e) v[e] *= rs;

  float4* o4 = (float4*)p;
  o4[2 * tid]     = make_float4(v[0], v[1], v[2], v[3]);
  o4[2 * tid + 1] = make_float4(v[4], v[5], v[6], v[7]);

  bf16x8 ob;
#pragma unroll
  for (int e = 0; e < 8; ++e) ob[e] = (short)bf16bits(v[e]);
  *(bf16x8*)&pb[8 * tid] = ob;
}

// ---------------------------------------------------------------------------
extern "C" void kernel_launch(void* const* d_in, const int* in_sizes, int n_in,
                              void* d_out, int out_size, void* d_ws, size_t ws_size,
                              hipStream_t stream) {
  const float* Q = (const float*)d_in[0];
  const float* K = (const float*)d_in[1];
  const float* V = (const float*)d_in[2];

  float* out     = (float*)d_out;                       // [B,S,H]
  float* weights = out + (size_t)Bb * Ss * Hh;          // [B,S,S]

  __hip_bfloat16* FQb = (__hip_bfloat16*)d_ws;
  __hip_bfloat16* FKb = FQb + (size_t)Bb * Ss * KP2;
  __hip_bfloat16* Vtb = FKb + (size_t)Bb * Ss * KP2;
  __hip_bfloat16* Wb  = (__hip_bfloat16*)d_ws;          // aliases dead FQb/FKb

  hipLaunchKernelGGL(fft_phase_kernel, dim3(Bb * Ss), dim3(256), 0, stream,
                     Q, K, FQb, FKb);
  hipLaunchKernelGGL(vt_kernel, dim3(Hh / 32, Ss / 32, Bb), dim3(256), 0, stream,
                     V, Vtb);
  hipLaunchKernelGGL((gemm256<KP2, KP2, KP2, Ss, 0, 256>), dim3(Ss / 256, Ss / 256, Bb),
                     dim3(512), 0, stream, FQb, FKb, weights,
                     (size_t)Ss * KP2, (size_t)Ss * KP2, (size_t)Ss * Ss);
  hipLaunchKernelGGL(softmax_kernel, dim3(Bb * Ss), dim3(256), 0, stream,
                     weights, Wb);
  hipLaunchKernelGGL((gemm256<Ss, Ss, Ss, Hh, 1, 128>), dim3(Hh / 128, Ss / 256, Bb),
                     dim3(512), 0, stream, Wb, Vtb, out,
                     (size_t)Ss * Ss, (size_t)Hh * Ss, (size_t)Ss * Hh);
}

// Round 7
// 169.288 us; speedup vs baseline: 1.2418x; 1.0019x over previous
//
#include <hip/hip_runtime.h>
#include <hip/hip_bf16.h>
#include <math.h>

// Problem constants
#define Bb 4
#define Ss 2048
#define Hh 1024
#define Ff 513           // H/2 + 1 rfft bins
#define FEAT 1026        // cos||sin feature length
#define KP2 1088         // padded feature K (17 * 64)

typedef __attribute__((ext_vector_type(8))) short bf16x8;
typedef __attribute__((ext_vector_type(4))) float f32x4;
typedef __attribute__((ext_vector_type(16))) float f32x16;

typedef const __attribute__((address_space(1))) void GVoid;
typedef __attribute__((address_space(3))) void LVoid;

// padded LDS index for float2 arrays: breaks power-of-2 stride conflicts
#define PADI(i) ((i) + ((i) >> 4))

__device__ __forceinline__ float2 cmul(float2 a, float2 b) {
  return make_float2(a.x * b.x - a.y * b.y, a.x * b.y + a.y * b.x);
}

__device__ __forceinline__ unsigned short bf16bits(float x) {
  __hip_bfloat16 h = __float2bfloat16(x);
  return *reinterpret_cast<unsigned short*>(&h);
}

// Inline-asm LDS read: opaque to the compiler's waitcnt insertion, so the
// counted-vmcnt pipeline is not silently drained (round-6 confirmed this).
// Ordering enforced manually: s_waitcnt lgkmcnt(0) + sched_barrier(0) before
// each MFMA cluster (rule #18), barriers around phases.
__device__ __forceinline__ bf16x8 lds_read_b128(const short* p) {
  bf16x8 r;
  asm volatile("ds_read_b128 %0, %1"
               : "=&v"(r)
               : "v"((const __attribute__((address_space(3))) short*)p));
  return r;
}

// ---------------------------------------------------------------------------
// Kernel 1: packed-real FFT. One block per (b,s) row-pair: z = Q_row + i*K_row,
// single 1024-pt radix-4 DIT FFT (5 stages), untangle, unit-normalize,
// emit bf16 [cos||sin] features.
// ---------------------------------------------------------------------------
__global__ __launch_bounds__(256) void fft_phase_kernel(
    const float* __restrict__ Q, const float* __restrict__ Kin,
    __hip_bfloat16* __restrict__ FQ, __hip_bfloat16* __restrict__ FK) {
  const int row = blockIdx.x;                     // 0 .. B*S-1
  const float* qs = Q   + (size_t)row * Hh;
  const float* ks = Kin + (size_t)row * Hh;
  __hip_bfloat16* fq = FQ + (size_t)row * KP2;
  __hip_bfloat16* fk = FK + (size_t)row * KP2;

  __shared__ float2 data[PADI(1023) + 1];
  __shared__ float2 tw[1024];
  const int tid = threadIdx.x;

#pragma unroll
  for (int e = 0; e < 4; ++e) {
    const int m = tid + e * 256;
    float s, c;
    sincosf(-6.283185307179586f * (float)m * (1.0f / 1024.0f), &s, &c);
    tw[m] = make_float2(c, s);
  }
#pragma unroll
  for (int e = 0; e < 4; ++e) {
    const int n = tid + e * 256;
    const int r4 = ((n & 3) << 8) | (((n >> 2) & 3) << 6) | (((n >> 4) & 3) << 4)
                 | (((n >> 6) & 3) << 2) | ((n >> 8) & 3);
    data[PADI(r4)] = make_float2(qs[n], ks[n]);
  }
  __syncthreads();

  int quarter = 1, step = 256;
  for (int s = 0; s < 5; ++s) {
    const int j = tid & (quarter - 1);
    const int pos = 4 * tid - 3 * j;
    const float2 x0 = data[PADI(pos)];
    const float2 x1 = data[PADI(pos + quarter)];
    const float2 x2 = data[PADI(pos + 2 * quarter)];
    const float2 x3 = data[PADI(pos + 3 * quarter)];
    const int e1 = j * step;
    const float2 a1 = cmul(x1, tw[e1]);
    const float2 a2 = cmul(x2, tw[2 * e1]);
    const float2 a3 = cmul(x3, tw[3 * e1]);
    const float2 t0 = make_float2(x0.x + a2.x, x0.y + a2.y);
    const float2 t1 = make_float2(x0.x - a2.x, x0.y - a2.y);
    const float2 t2 = make_float2(a1.x + a3.x, a1.y + a3.y);
    const float2 t3 = make_float2(a1.x - a3.x, a1.y - a3.y);
    data[PADI(pos)]               = make_float2(t0.x + t2.x, t0.y + t2.y);
    data[PADI(pos + quarter)]     = make_float2(t1.x + t3.y, t1.y - t3.x);
    data[PADI(pos + 2 * quarter)] = make_float2(t0.x - t2.x, t0.y - t2.y);
    data[PADI(pos + 3 * quarter)] = make_float2(t1.x - t3.y, t1.y + t3.x);
    __syncthreads();
    quarter <<= 2; step >>= 2;
  }

  for (int f = tid; f <= 512; f += 256) {
    const float2 z1 = data[PADI(f)];
    const float2 z2 = data[PADI((1024 - f) & 1023)];
    const float qr = z1.x + z2.x, qi = z1.y - z2.y;
    const float kr = z1.y + z2.y, ki = z2.x - z1.x;
    float qc, qsn, kc, ksn;
    const float qm2 = qr * qr + qi * qi;
    if (qm2 > 1e-30f) { const float iv = rsqrtf(qm2); qc = qr * iv; qsn = qi * iv; }
    else              { qc = 1.0f; qsn = 0.0f; }
    const float km2 = kr * kr + ki * ki;
    if (km2 > 1e-30f) { const float iv = rsqrtf(km2); kc = kr * iv; ksn = ki * iv; }
    else              { kc = 1.0f; ksn = 0.0f; }
    fq[f] = __float2bfloat16(qc); fq[Ff + f] = __float2bfloat16(qsn);
    fk[f] = __float2bfloat16(kc); fk[Ff + f] = __float2bfloat16(ksn);
  }
  for (int p = FEAT + tid; p < KP2; p += 256) {
    fq[p] = __float2bfloat16(0.0f);
    fk[p] = __float2bfloat16(0.0f);
  }
}

// ---------------------------------------------------------------------------
// Kernel 2: V [B,S,H] fp32 -> Vt [B,H,S] bf16 (transpose, LDS 32x33 tile)
// ---------------------------------------------------------------------------
__global__ __launch_bounds__(256) void vt_kernel(
    const float* __restrict__ V, __hip_bfloat16* __restrict__ Vt) {
  const int b = blockIdx.z;
  const int h0 = blockIdx.x * 32;
  const int s0 = blockIdx.y * 32;
  __shared__ float t[32][33];
  const int tid = threadIdx.x;
  const int c = tid & 31;
  const int r8 = tid >> 5;
  const float* Vb = V + (size_t)b * Ss * Hh;
#pragma unroll
  for (int e = 0; e < 4; ++e) {
    const int r = r8 + e * 8;
    t[r][c] = Vb[(size_t)(s0 + r) * Hh + h0 + c];
  }
  __syncthreads();
  __hip_bfloat16* O = Vt + (size_t)b * Hh * Ss;
#pragma unroll
  for (int e = 0; e < 4; ++e) {
    const int hh = r8 + e * 8;
    O[(size_t)(h0 + hh) * Ss + s0 + c] = __float2bfloat16(t[c][hh]);
  }
}

// ---------------------------------------------------------------------------
// bf16 MFMA GEMM (32x32x16), C = A * B^T, BMT x 256 tile, BK=64, 8 waves
// (2M x 4N), 4 phases/K-tile with counted vmcnt (T3+T4) + setprio (T5) +
// bijective XCD swizzle (T1; nwg % 8 == 0).
// Why 32x32x16 (round-6 post-mortem): per phase the CU's LDS pipe served
// ~2x the cycles of its MFMA pipe with 16x16x32 frags; 32x32x16 halves
// ds_read_b128 per FLOP and uses the faster 32x32 pipe (2382 TF).
// LDS layout per buffer: [rg][kc][k8][row][8bf16] subtiles of 1KB; the
// global_load_lds linear lane write (lane*16B) == ds_read addressing
// (lane*16B) == MFMA operand order (row=lane&31, k8=lane>>5) -> conflict-
// free, swizzle-free. k-permutation identical on A and B frags -> cancels.
// Chunk lifetimes (4-phase): B-kh0 last read ph0, A-kh0 ph1, B-kh1 ph2,
// A-kh1 ph3; stages: ph0 A-kh1(t+1)->buf^1, ph1 B-kh0(t+2), ph2 A-kh0(t+2),
// ph3 B-kh1(t+2). ph3 steady vmcnt = loads of ph1..3 = 2+SAW+2.
// C/D layout [m74/m101]: col=lane&31, row=(reg&3)+8*(reg>>2)+4*(lane>>5).
// EPI 0: C = acc/513 (scores; +1 dropped, softmax shift-invariant).
// EPI 1: C = acc (PV).
// ---------------------------------------------------------------------------
template<int K, int LDA, int LDB, int LDC, int EPI, int BMT>
__global__ __launch_bounds__(512, 2) void gemm32(
    const __hip_bfloat16* __restrict__ Ag, const __hip_bfloat16* __restrict__ Bg,
    float* __restrict__ Cg, size_t strA, size_t strB, size_t strC) {
  constexpr int nt  = K / 64;
  constexpr int MF  = BMT / 64;   // m-frags per wave (score 4, PV 2)
  constexpr int MPH = MF / 2;     // m-frags per phase (2, 1)
  constexpr int SAW = MPH;        // SA instr per wave per chunk (2, 1)

  // bijective XCD swizzle: consecutive processed tiles land on one XCD's L2
  const int gx = gridDim.x, gy = gridDim.y;
  const int nwg = gx * gy * (int)gridDim.z;
  int f = ((int)blockIdx.z * gy + (int)blockIdx.y) * gx + (int)blockIdx.x;
  f = (f & 7) * (nwg >> 3) + (f >> 3);
  const int bx = f % gx; f /= gx;
  const int by = f % gy;
  const int bz = f / gy;

  const int i0 = by * BMT;
  const int j0 = bx * 256;
  const char* Ab = (const char*)(Ag + (size_t)bz * strA);
  const char* Bp = (const char*)(Bg + (size_t)bz * strB);
  float* C = Cg + (size_t)bz * strC;

  __shared__ short As[2][BMT * 64];   // [rg][kc][512] subtiles
  __shared__ short Bs[2][256 * 64];

  const int tid = threadIdx.x;
  const int lane = tid & 63;
  const int w  = tid >> 6;        // wave 0..7
  const int wm = w >> 2;          // 0..1 (M)
  const int wn = w & 3;           // 0..3 (N)

  f32x16 acc[MF][2];
#pragma unroll
  for (int mi = 0; mi < MF; ++mi)
#pragma unroll
    for (int ni = 0; ni < 2; ++ni)
#pragma unroll
      for (int r = 0; r < 16; ++r) acc[mi][ni][r] = 0.0f;

#define BAR() __builtin_amdgcn_s_barrier()

  // stage A/B chunk (khalf kh = 2 k-chunks) of K-tile tt into buffer dd
#define SA(dd, tt, kh)                                                                   \
  do {                                                                                   \
    _Pragma("unroll")                                                                    \
    for (int ii = 0; ii < SAW; ++ii) {                                                   \
      const int f_ = w * SAW + ii;                                                       \
      const int rg_ = f_ >> 1;                                                           \
      const int kc_ = 2 * (kh) + (f_ & 1);                                               \
      __builtin_amdgcn_global_load_lds(                                                  \
          (GVoid*)(Ab + (size_t)(i0 + rg_ * 32 + (lane & 31)) * (LDA * 2) +              \
                   (size_t)(tt) * 128 + kc_ * 32 + (lane >> 5) * 16),                    \
          (LVoid*)&As[dd][(rg_ * 4 + kc_) * 512], 16, 0, 0);                             \
    }                                                                                    \
  } while (0)
#define SB(dd, tt, kh)                                                                   \
  do {                                                                                   \
    _Pragma("unroll")                                                                    \
    for (int ii = 0; ii < 2; ++ii) {                                                     \
      const int f_ = w * 2 + ii;                                                         \
      const int rg_ = f_ >> 1;                                                           \
      const int kc_ = 2 * (kh) + (f_ & 1);                                               \
      __builtin_amdgcn_global_lo\
ad_lds(                                                                                  \
          (GVoid*)(Bp + (size_t)(j0 + rg_ * 32 + (lane & 31)) * (LDB * 2) +              \
                   (size_t)(tt) * 128 + kc_ * 32 + (lane >> 5) * 16),                    \
          (LVoid*)&Bs[dd][(rg_ * 4 + kc_) * 512], 16, 0, 0);                             \
    }                                                                                    \
  } while (0)
#define RA(dd, mh, kh)                                                                   \
  _Pragma("unroll")                                                                      \
  for (int mi = 0; mi < MPH; ++mi)                                                       \
    _Pragma("unroll")                                                                    \
    for (int kb = 0; kb < 2; ++kb)                                                       \
      af[mi][kb] = lds_read_b128(                                                        \
          &As[dd][((wm * MF + (mh) * MPH + mi) * 4 + 2 * (kh) + kb) * 512 + lane * 8]);
#define RB(dd, kh)                                                                       \
  _Pragma("unroll")                                                                      \
  for (int ni = 0; ni < 2; ++ni)                                                         \
    _Pragma("unroll")                                                                    \
    for (int kb = 0; kb < 2; ++kb)                                                       \
      bf[ni][kb] = lds_read_b128(                                                        \
          &Bs[dd][((wn * 2 + ni) * 4 + 2 * (kh) + kb) * 512 + lane * 8]);
#define MM(mh)                                                                           \
  asm volatile("s_waitcnt lgkmcnt(0)");                                                  \
  __builtin_amdgcn_sched_barrier(0);                                                     \
  __builtin_amdgcn_s_setprio(1);                                                         \
  _Pragma("unroll")                                                                      \
  for (int mi = 0; mi < MPH; ++mi)                                                       \
    _Pragma("unroll")                                                                    \
    for (int ni = 0; ni < 2; ++ni)                                                       \
      _Pragma("unroll")                                                                  \
      for (int kb = 0; kb < 2; ++kb)                                                     \
        acc[(mh) * MPH + mi][ni] = __builtin_amdgcn_mfma_f32_32x32x16_bf16(              \
            af[mi][kb], bf[ni][kb], acc[(mh) * MPH + mi][ni], 0, 0, 0);                  \
  __builtin_amdgcn_s_setprio(0);                                                         \
  __builtin_amdgcn_sched_barrier(0);

  // prologue: stage tiles 0 and 1 fully; wait until only tile-1's remain
  SA(0, 0, 0); SA(0, 0, 1); SB(0, 0, 0); SB(0, 0, 1);
  SA(1, 1, 0); SA(1, 1, 1); SB(1, 1, 0); SB(1, 1, 1);
  if constexpr (SAW == 2) asm volatile("s_waitcnt vmcnt(8)");
  else                    asm volatile("s_waitcnt vmcnt(6)");
  BAR();

  for (int t = 0; t < nt; ++t) {
    const int d = t & 1;
    bf16x8 af[MPH][2], bf[2][2];

    // ---- phase 0: kh0, m-half 0
    RA(d, 0, 0); RB(d, 0);
    if (t >= 1 && t + 1 < nt) SA(d ^ 1, t + 1, 1);
    BAR();
    MM(0);
    BAR();

    // ---- phase 1: kh0, m-half 1 (reuse bf)
    RA(d, 1, 0);
    if (t + 2 < nt) SB(d, t + 2, 0);
    BAR();
    MM(1);
    BAR();

    // ---- phase 2: kh1, m-half 0
    RA(d, 0, 1); RB(d, 1);
    if (t + 2 < nt) SA(d, t + 2, 0);
    BAR();
    MM(0);
    BAR();

    // ---- phase 3: kh1, m-half 1 (reuse bf)
    RA(d, 1, 1);
    if (t + 2 < nt) SB(d, t + 2, 1);
    BAR();
    MM(1);
    if (t + 2 < nt) {
      if constexpr (SAW == 2) asm volatile("s_waitcnt vmcnt(6)");
      else                    asm volatile("s_waitcnt vmcnt(5)");
    } else {
      asm volatile("s_waitcnt vmcnt(0)");
    }
    BAR();
  }
#undef SA
#undef SB
#undef RA
#undef RB
#undef MM
#undef BAR

  // epilogue: 32x32 C/D layout [m74/m101]
  const int col = lane & 31;
  const int rbase = (lane >> 5) * 4;
#pragma unroll
  for (int mi = 0; mi < MF; ++mi) {
#pragma unroll
    for (int ni = 0; ni < 2; ++ni) {
#pragma unroll
      for (int r = 0; r < 16; ++r) {
        const int row = (r & 3) + 8 * (r >> 2) + rbase;
        const int i = i0 + wm * (MF * 32) + mi * 32 + row;
        const int j = j0 + wn * 64 + ni * 32 + col;
        float v = acc[mi][ni][r];
        if (EPI == 0) v *= (1.0f / 513.0f);
        C[(size_t)i * LDC + j] = v;
      }
    }
  }
}

// ---------------------------------------------------------------------------
// Kernel 3: in-place row softmax over 2048 cols + bf16 copy for PV GEMM.
// ---------------------------------------------------------------------------
__global__ __launch_bounds__(256) void softmax_kernel(
    float* __restrict__ W, __hip_bfloat16* __restrict__ Wb) {
  const size_t row = blockIdx.x;
  float* p = W + row * (size_t)Ss;
  __hip_bfloat16* pb = Wb + row * (size_t)Ss;
  const int tid = threadIdx.x;
  __shared__ float red[4];

  const float4* p4 = (const float4*)p;
  const float4 a = p4[2 * tid];
  const float4 bq = p4[2 * tid + 1];
  float v[8] = {a.x, a.y, a.z, a.w, bq.x, bq.y, bq.z, bq.w};

  float m = v[0];
#pragma unroll
  for (int e = 1; e < 8; ++e) m = fmaxf(m, v[e]);
#pragma unroll
  for (int off = 32; off > 0; off >>= 1) m = fmaxf(m, __shfl_xor(m, off, 64));
  if ((tid & 63) == 0) red[tid >> 6] = m;
  __syncthreads();
  m = fmaxf(fmaxf(red[0], red[1]), fmaxf(red[2], red[3]));

  float sum = 0.0f;
#pragma unroll
  for (int e = 0; e < 8; ++e) { v[e] = __expf(v[e] - m); sum += v[e]; }
#pragma unroll
  for (int off = 32; off > 0; off >>= 1) sum += __shfl_xor(sum, off, 64);
  __syncthreads();
  if ((tid & 63) == 0) red[tid >> 6] = sum;
  __syncthreads();
  sum = red[0] + red[1] + red[2] + red[3];

  const float rs = 1.0f / sum;
#pragma unroll
  for (int e = 0; e < 8; ++e) v[e] *= rs;

  float4* o4 = (float4*)p;
  o4[2 * tid]     = make_float4(v[0], v[1], v[2], v[3]);
  o4[2 * tid + 1] = make_float4(v[4], v[5], v[6], v[7]);

  bf16x8 ob;
#pragma unroll
  for (int e = 0; e < 8; ++e) ob[e] = (short)bf16bits(v[e]);
  *(bf16x8*)&pb[8 * tid] = ob;
}

// ---------------------------------------------------------------------------
extern "C" void kernel_launch(void* const* d_in, const int* in_sizes, int n_in,
                              void* d_out, int out_size, void* d_ws, size_t ws_size,
                              hipStream_t stream) {
  const float* Q = (const float*)d_in[0];
  const float* K = (const float*)d_in[1];
  const float* V = (const float*)d_in[2];

  float* out     = (float*)d_out;                       // [B,S,H]
  float* weights = out + (size_t)Bb * Ss * Hh;          // [B,S,S]

  __hip_bfloat16* FQb = (__hip_bfloat16*)d_ws;
  __hip_bfloat16* FKb = FQb + (size_t)Bb * Ss * KP2;
  __hip_bfloat16* Vtb = FKb + (size_t)Bb * Ss * KP2;
  __hip_bfloat16* Wb  = (__hip_bfloat16*)d_ws;          // aliases dead FQb/FKb

  hipLaunchKernelGGL(fft_phase_kernel, dim3(Bb * Ss), dim3(256), 0, stream,
                     Q, K, FQb, FKb);
  hipLaunchKernelGGL(vt_kernel, dim3(Hh / 32, Ss / 32, Bb), dim3(256), 0, stream,
                     V, Vtb);
  // score: 256x256 tiles, grid 8x8x4 = 256 WGs
  hipLaunchKernelGGL((gemm32<KP2, KP2, KP2, Ss, 0, 256>), dim3(Ss / 256, Ss / 256, Bb),
                     dim3(512), 0, stream, FQb, FKb, weights,
                     (size_t)Ss * KP2, (size_t)Ss * KP2, (size_t)Ss * Ss);
  hipLaunchKernelGGL(softmax_kernel, dim3(Bb * Ss), dim3(256), 0, stream,
                     weights, Wb);
  // PV: 128x256 tiles, grid 4x16x4 = 256 WGs (square 64x64 wave tiles)
  hipLaunchKernelGGL((gemm32<Ss, Ss, Ss, Hh, 1, 128>), dim3(Hh / 256, Ss / 128, Bb),
                     dim3(512), 0, stream, Wb, Vtb, out,
                     (size_t)Ss * Ss, (size_t)Hh * Ss, (size_t)Ss * Hh);
}